// Round 9
// baseline (534.253 us; speedup 1.0000x reference)
//
#include <hip/hip_runtime.h>
#include <cstdint>
#include <cstddef>

#define BB 32
#define NN 4096
#define DD 256
#define KK 16

constexpr int TILE  = 64;             // tokens per block
constexpr int SUB   = 16;             // tokens per staged sub-tile
constexpr int NSUB  = TILE / SUB;     // 4
constexpr int TPBAT = NN / TILE;      // 64
constexpr int TILES = BB * TPBAT;     // 2048
constexpr int ROWF  = DD + 4;         // padded LDS row (260 floats)
constexpr float FEPS = 1e-12f;

__device__ __forceinline__ float dot4(float4 a, float4 b) {
  return a.x*b.x + a.y*b.y + a.z*b.z + a.w*b.w;
}
__device__ __forceinline__ float4 f4add(float4 a, float4 b) {
  return make_float4(a.x+b.x, a.y+b.y, a.z+b.z, a.w+b.w);
}
__device__ __forceinline__ float4 f4fma(float s, float4 x, float4 a) {
  a.x += s*x.x; a.y += s*x.y; a.z += s*x.z; a.w += s*x.w; return a;
}

// ---------------------------------------------------------------------------
// Fused kernel: TILE=64 tokens/block, 256 threads, 4 blocks/CU.
// Per 16-token sub-tile (double-buffered LDS, pad-260 rows, reg-staged):
//   Phase A: thread = (token-pair, dim-half, k): logits via LDS broadcasts +
//            L1-hot W; softmax pure-shfl.
//   Phase B: thread = (dim-quad, all k): acc[16] f4; wave handles 4 tokens;
//            x LDS-read once; al wave-uniform broadcast.
// Epilogue: 2-step LDS cross-wave combine; wave 0 writes coalesced partial.
// ---------------------------------------------------------------------------
__global__ __launch_bounds__(256, 4) void fused_kernel(
    const float* __restrict__ x, const int* __restrict__ mask,
    const float* __restrict__ W, const float* __restrict__ bias,
    float* __restrict__ outv, float* __restrict__ outs, int partial_mode)
{
  __shared__ float xs[2][SUB * ROWF];   // 2 x 16.25 KB
  __shared__ float al[SUB * KK];        // 1 KB assigns
  __shared__ float asacc[4][KK];        // asum wave partials

  const int tid  = threadIdx.x;
  const int lane = tid & 63;
  const int wave = tid >> 6;
  // Phase A ids
  const int tp = tid >> 5;              // token pair 0..7
  const int dc = (tid >> 4) & 1;        // dim half
  const int k  = tid & 15;              // cluster
  // Phase B id
  const int dq = lane;                  // dim quad 0..63

  const int tile = blockIdx.x;
  const int b    = tile / TPBAT;
  const int n0   = (tile % TPBAT) * TILE;

  const float4* xb4 = reinterpret_cast<const float4*>(x + ((size_t)b*NN + n0)*DD);
  const int*    mb  = mask + (size_t)b*NN + n0;

  const float  bk = bias[k];
  const float* Wp = W + k * DD + dc * 128;

  float4 acc[KK];
#pragma unroll
  for (int q = 0; q < KK; ++q) acc[q] = make_float4(0.f, 0.f, 0.f, 0.f);
  float sA = 0.f;

  // prologue: stage sub-tile 0 into buffer 0 (padded rows)
  {
    const float4 s0 = xb4[tid], s1 = xb4[tid+256], s2 = xb4[tid+512], s3 = xb4[tid+768];
    float* d = xs[0];
    int i;
    i = tid;       *reinterpret_cast<float4*>(d + (i>>6)*ROWF + (i&63)*4) = s0;
    i = tid + 256; *reinterpret_cast<float4*>(d + (i>>6)*ROWF + (i&63)*4) = s1;
    i = tid + 512; *reinterpret_cast<float4*>(d + (i>>6)*ROWF + (i&63)*4) = s2;
    i = tid + 768; *reinterpret_cast<float4*>(d + (i>>6)*ROWF + (i&63)*4) = s3;
  }

  int cur = 0;
#pragma unroll 1
  for (int st = 0; st < NSUB; ++st) {
    __syncthreads();                    // staged sub-tile visible (implicit drain)
    const float* xsc = xs[cur];

    // ---- Phase A: logits for tokens 2tp, 2tp+1 over dim-half dc ----------
    const float* rowA = xsc + (2*tp) * ROWF + dc * 128;
    const float* rowB = rowA + ROWF;
    float pa0 = 0.f, pa1 = 0.f, pb0 = 0.f, pb1 = 0.f;
#pragma unroll
    for (int j = 0; j < 32; ++j) {
      const float4 wv = *reinterpret_cast<const float4*>(Wp   + j*4);
      const float4 xa = *reinterpret_cast<const float4*>(rowA + j*4);
      const float4 xb = *reinterpret_cast<const float4*>(rowB + j*4);
      if (j & 1) { pa1 += dot4(xa, wv); pb1 += dot4(xb, wv); }
      else       { pa0 += dot4(xa, wv); pb0 += dot4(xb, wv); }
    }
    float la = pa0 + pa1, lb = pb0 + pb1;
    la += __shfl_xor(la, 16);           // combine dim halves
    lb += __shfl_xor(lb, 16);
    const float ea = __expf(la + bk), eb = __expf(lb + bk);
    float sa = ea, sb = eb;
    sa += __shfl_xor(sa, 1); sb += __shfl_xor(sb, 1);
    sa += __shfl_xor(sa, 2); sb += __shfl_xor(sb, 2);
    sa += __shfl_xor(sa, 4); sb += __shfl_xor(sb, 4);
    sa += __shfl_xor(sa, 8); sb += __shfl_xor(sb, 8);
    const int mva = mb[st*SUB + 2*tp + 0];
    const int mvb = mb[st*SUB + 2*tp + 1];
    const float aa = mva ? ea * (1.0f / sa) : 0.0f;
    const float ab = mvb ? eb * (1.0f / sb) : 0.0f;
    sA += aa + ab;                      // dc-duplicated; halved at the end
    if (dc == 0) {
      al[(2*tp + 0) * KK + k] = aa;
      al[(2*tp + 1) * KK + k] = ab;
    }
    __syncthreads();                    // al visible

    // ---- issue next sub-tile's loads (hide under Phase B) ----------------
    float4 s0, s1, s2, s3;
    if (st < NSUB - 1) {
      const float4* g4 = xb4 + (size_t)(st + 1) * (SUB * 64);
      s0 = g4[tid]; s1 = g4[tid+256]; s2 = g4[tid+512]; s3 = g4[tid+768];
    }

    // ---- Phase B: acc[k] += a[tok][k] * x[tok][4dq..4dq+3] ---------------
#pragma unroll
    for (int t = 0; t < 4; ++t) {
      const int tok = wave + 4*t;       // wave-uniform
      const float4 xv = *reinterpret_cast<const float4*>(xsc + tok*ROWF + 4*dq);
#pragma unroll
      for (int q = 0; q < 4; ++q) {
        const float4 av = *reinterpret_cast<const float4*>(al + tok*KK + 4*q);
        acc[4*q+0] = f4fma(av.x, xv, acc[4*q+0]);
        acc[4*q+1] = f4fma(av.y, xv, acc[4*q+1]);
        acc[4*q+2] = f4fma(av.z, xv, acc[4*q+2]);
        acc[4*q+3] = f4fma(av.w, xv, acc[4*q+3]);
      }
    }

    // ---- land next sub-tile into the other buffer ------------------------
    if (st < NSUB - 1) {
      float* d = xs[cur ^ 1];
      int i;
      i = tid;       *reinterpret_cast<float4*>(d + (i>>6)*ROWF + (i&63)*4) = s0;
      i = tid + 256; *reinterpret_cast<float4*>(d + (i>>6)*ROWF + (i&63)*4) = s1;
      i = tid + 512; *reinterpret_cast<float4*>(d + (i>>6)*ROWF + (i&63)*4) = s2;
      i = tid + 768; *reinterpret_cast<float4*>(d + (i>>6)*ROWF + (i&63)*4) = s3;
    }
    cur ^= 1;
  }

  // ---------------- epilogue: cross-wave combine --------------------------
  __syncthreads();                      // everyone done with xs / al
  float* cmb0 = &xs[0][0];              // flat 4096-float regions
  float* cmb1 = &xs[1][0];

  // asum wave partials (sum over dc and tp-low via shfl)
  float sred = sA;
  sred += __shfl_xor(sred, 16);
  sred += __shfl_xor(sred, 32);
  if (lane < KK) asacc[wave][lane] = sred;

  if (wave == 1) {
#pragma unroll
    for (int q = 0; q < KK; ++q)
      *reinterpret_cast<float4*>(cmb0 + q*DD + 4*dq) = acc[q];
  }
  if (wave == 3) {
#pragma unroll
    for (int q = 0; q < KK; ++q)
      *reinterpret_cast<float4*>(cmb1 + q*DD + 4*dq) = acc[q];
  }
  __syncthreads();
  if (wave == 0) {
#pragma unroll
    for (int q = 0; q < KK; ++q)
      acc[q] = f4add(acc[q], *reinterpret_cast<const float4*>(cmb0 + q*DD + 4*dq));
  }
  if (wave == 2) {
#pragma unroll
    for (int q = 0; q < KK; ++q)
      acc[q] = f4add(acc[q], *reinterpret_cast<const float4*>(cmb1 + q*DD + 4*dq));
  }
  __syncthreads();
  if (wave == 2) {
#pragma unroll
    for (int q = 0; q < KK; ++q)
      *reinterpret_cast<float4*>(cmb0 + q*DD + 4*dq) = acc[q];
  }
  __syncthreads();

  if (wave == 0) {
#pragma unroll
    for (int q = 0; q < KK; ++q)
      acc[q] = f4add(acc[q], *reinterpret_cast<const float4*>(cmb0 + q*DD + 4*dq));
    if (partial_mode) {
      float4* dst = reinterpret_cast<float4*>(outv + (size_t)tile * KK * DD);
#pragma unroll
      for (int q = 0; q < KK; ++q) dst[q*64 + dq] = acc[q];  // coalesced
    } else {
      float* vb = outv + (size_t)b * KK * DD;
#pragma unroll
      for (int q = 0; q < KK; ++q) {
        float* p = vb + q * DD + 4*dq;
        atomicAdd(p + 0, acc[q].x);
        atomicAdd(p + 1, acc[q].y);
        atomicAdd(p + 2, acc[q].z);
        atomicAdd(p + 3, acc[q].w);
      }
    }
  }
  if (tid < KK) {
    const float s = (asacc[0][tid] + asacc[1][tid] +
                     asacc[2][tid] + asacc[3][tid]) * 0.5f;
    if (partial_mode) outs[tile * KK + tid] = s;
    else              atomicAdd(&outs[b * KK + tid], s);
  }
}

// ---------------------------------------------------------------------------
// Finalize A (BB*KK blocks x 256 thr): block = (b,k). float4 slice-sum with
// 4 slice-groups x 4 accumulators, LDS combine, ssum by wave butterfly.
// ---------------------------------------------------------------------------
__global__ __launch_bounds__(256) void finalizeA_kernel(
    const float* __restrict__ pv, const float* __restrict__ ps,
    const float* __restrict__ cent, float* __restrict__ vtmp,
    float* __restrict__ ssbuf, int nslice)
{
  const int blk = blockIdx.x;
  const int b   = blk >> 4;
  const int k   = blk & 15;
  const int tid = threadIdx.x;
  const int sg  = tid >> 6;           // slice group 0..3
  const int ld  = tid & 63;           // float4 dim index

  __shared__ float4 cmbA[3][64];

  float pval = 0.f;
  for (int s = ld; s < nslice; s += 64)
    pval += ps[(size_t)(b * nslice + s) * KK + k];
#pragma unroll
  for (int off = 32; off >= 1; off >>= 1) pval += __shfl_xor(pval, off);
  const float ssum = pval;

  const float4* pv4 = reinterpret_cast<const float4*>(pv);
  const size_t base = ((size_t)b * nslice * KK + k) * 64 + ld;
  float4 a0 = make_float4(0.f,0.f,0.f,0.f), a1 = a0, a2 = a0, a3 = a0;
  int s = sg;
  for (; s + 12 < nslice; s += 16) {
    a0 = f4add(a0, pv4[base + (size_t)(s     ) * (KK * 64)]);
    a1 = f4add(a1, pv4[base + (size_t)(s +  4) * (KK * 64)]);
    a2 = f4add(a2, pv4[base + (size_t)(s +  8) * (KK * 64)]);
    a3 = f4add(a3, pv4[base + (size_t)(s + 12) * (KK * 64)]);
  }
  for (; s < nslice; s += 4)
    a0 = f4add(a0, pv4[base + (size_t)s * (KK * 64)]);
  float4 tot = f4add(f4add(a0, a1), f4add(a2, a3));

  if (sg > 0) cmbA[sg - 1][ld] = tot;
  __syncthreads();

  if (sg == 0) {
    tot = f4add(tot, f4add(cmbA[0][ld], f4add(cmbA[1][ld], cmbA[2][ld])));
    const float4 cv = reinterpret_cast<const float4*>(cent)[k * 64 + ld];
    float4 v;
    v.x = tot.x - ssum * cv.x;
    v.y = tot.y - ssum * cv.y;
    v.z = tot.z - ssum * cv.z;
    v.w = tot.w - ssum * cv.w;
    reinterpret_cast<float4*>(vtmp)[((size_t)b * KK + k) * 64 + ld] = v;
    float p = dot4(v, v);
#pragma unroll
    for (int off = 32; off >= 1; off >>= 1) p += __shfl_xor(p, off);
    if (ld == 0) ssbuf[blk] = p;
  }
}

// ---------------------------------------------------------------------------
// Finalize B (BB blocks x 1024 thr): intra-cluster + global L2 normalize.
// ---------------------------------------------------------------------------
__global__ __launch_bounds__(1024) void finalizeB_kernel(
    const float* __restrict__ vtmp, const float* __restrict__ ssbuf,
    float* __restrict__ out)
{
  const int b    = blockIdx.x;
  const int tid  = threadIdx.x;
  const int d    = tid & 255;
  const int kq   = tid >> 8;
  const int lane = tid & 63;
  const int w    = tid >> 6;

  __shared__ float redB[16];
  __shared__ float gsh;

  float u[4];
  float p2 = 0.f;
#pragma unroll
  for (int kk = 0; kk < 4; ++kk) {
    const int k = kq * 4 + kk;
    const float rk = 1.0f / fmaxf(sqrtf(ssbuf[b * KK + k]), FEPS);
    u[kk] = vtmp[((size_t)b * KK + k) * DD + d] * rk;
    p2 += u[kk] * u[kk];
  }
#pragma unroll
  for (int off = 32; off >= 1; off >>= 1) p2 += __shfl_xor(p2, off);
  if (lane == 0) redB[w] = p2;
  __syncthreads();

  if (tid == 0) {
    float g = 0.f;
#pragma unroll
    for (int i = 0; i < 16; ++i) g += redB[i];
    gsh = 1.0f / fmaxf(sqrtf(g), FEPS);
  }
  __syncthreads();

  const float g = gsh;
#pragma unroll
  for (int kk = 0; kk < 4; ++kk) {
    const int k = kq * 4 + kk;
    out[(size_t)b * KK * DD + k * DD + d] = u[kk] * g;
  }
}

extern "C" void kernel_launch(void* const* d_in, const int* in_sizes, int n_in,
                              void* d_out, int out_size, void* d_ws, size_t ws_size,
                              hipStream_t stream) {
  const float* x    = (const float*)d_in[0];
  const int*   mask = (const int*)d_in[1];
  const float* W    = (const float*)d_in[2];
  const float* bias = (const float*)d_in[3];
  const float* cent = (const float*)d_in[4];
  float* out = (float*)d_out;

  const size_t vtmpN = (size_t)BB * KK * DD;
  const size_t ssN   = (size_t)BB * KK;
  const size_t need  = ((size_t)TILES * KK * DD + (size_t)TILES * KK
                        + vtmpN + ssN) * sizeof(float);

  if (ws_size >= need) {
    float* pv    = (float*)d_ws;
    float* ps    = pv + (size_t)TILES * KK * DD;
    float* vtmp  = ps + (size_t)TILES * KK;
    float* ssbuf = vtmp + vtmpN;
    fused_kernel<<<TILES, 256, 0, stream>>>(x, mask, W, bias, pv, ps, 1);
    finalizeA_kernel<<<BB * KK, 256, 0, stream>>>(pv, ps, cent, vtmp, ssbuf, TPBAT);
    finalizeB_kernel<<<BB, 1024, 0, stream>>>(vtmp, ssbuf, out);
  } else {
    float* vacc  = (float*)d_ws;                 // [BB][KK][DD]
    float* sacc  = vacc + vtmpN;                 // [BB][KK]
    float* vtmp  = sacc + ssN;
    float* ssbuf = vtmp + vtmpN;
    hipMemsetAsync(d_ws, 0, (vtmpN + ssN) * sizeof(float), stream);
    fused_kernel<<<TILES, 256, 0, stream>>>(x, mask, W, bias, vacc, sacc, 0);
    finalizeA_kernel<<<BB * KK, 256, 0, stream>>>(vacc, sacc, cent, vtmp, ssbuf, 1);
    finalizeB_kernel<<<BB, 1024, 0, stream>>>(vtmp, ssbuf, out);
  }
}

// Round 10
// 63.053 us; speedup vs baseline: 8.4731x; 8.4731x over previous
//
#include <hip/hip_runtime.h>
#include <cstdint>
#include <cstddef>

#define BB 32
#define NN 4096
#define DD 256
#define KK 16

constexpr float FEPS = 1e-12f;

__device__ __forceinline__ float dot4(float4 a, float4 b) {
  return a.x*b.x + a.y*b.y + a.z*b.z + a.w*b.w;
}
__device__ __forceinline__ float4 f4add(float4 a, float4 b) {
  return make_float4(a.x+b.x, a.y+b.y, a.z+b.z, a.w+b.w);
}
__device__ __forceinline__ float4 f4fma(float s, float4 x, float4 a) {
  a.x += s*x.x; a.y += s*x.y; a.z += s*x.z; a.w += s*x.w; return a;
}

// ---------------------------------------------------------------------------
// Fused kernel (r7 structure): TILE tokens per block, 256 threads, 8 blk/CU.
// Phase A: thread = (token, k-group): KPT logits; x staged via double-buffered
//          16-dim LDS chunks (pad 4->5 float4: <=2-way banks = free).
// Phase B: wave = k-quad over ALL TILE tokens, x streamed from global
//          (L1/L2-hot) through a rolling 4-deep register pipeline.
// ---------------------------------------------------------------------------
template <int TILE>
__global__ __launch_bounds__(256, (TILE == 64 ? 8 : 4)) void fused_kernel(
    const float* __restrict__ x, const int* __restrict__ mask,
    const float* __restrict__ W, const float* __restrict__ bias,
    float* __restrict__ outv, float* __restrict__ outs, int partial_mode)
{
  constexpr int NG    = 256 / TILE;     // k-groups (thread layers)
  constexpr int KPT   = KK / NG;        // k per thread in Phase A
  constexpr int SW4   = TILE / 64;      // staging float4s per thread per chunk
  constexpr int WPG   = 4 / NG;         // waves per k-group
  constexpr int TPBAT = NN / TILE;

  __shared__ float4 xs4[2][TILE * 5];   // 2 x 5*TILE float4 (pad 4->5)
  __shared__ float  al[TILE * KK];
  __shared__ float  psum[TILE][NG];
  __shared__ float  asacc[WPG][KK];

  const int tid  = threadIdx.x;
  const int lane = tid & 63;
  const int wave = tid >> 6;
  const int tok  = tid & (TILE - 1);
  const int kg   = __builtin_amdgcn_readfirstlane(tid / TILE);
  const int slot = __builtin_amdgcn_readfirstlane(wave & (WPG - 1));

  const int tile = blockIdx.x;
  const int b    = tile / TPBAT;
  const int n0   = (tile % TPBAT) * TILE;

  const float4* xb4 = reinterpret_cast<const float4*>(x + ((size_t)b*NN + n0)*DD);
  const int*    mb  = mask + (size_t)b*NN + n0;

  // ---------------- Phase A: KPT logits per thread, dbuf staging ----------
  float part[KPT];
#pragma unroll
  for (int q = 0; q < KPT; ++q) part[q] = bias[kg * KPT + q];

  const int st = tid >> 2;              // staging token (0..63)
  const int sj = tid & 3;               // staging float4 col within chunk

  // prologue: stage chunk 0 into buffer 0
  {
    float4 pre[SW4];
#pragma unroll
    for (int l = 0; l < SW4; ++l)
      pre[l] = xb4[(size_t)(st + l * 64) * 64 + sj];
#pragma unroll
    for (int l = 0; l < SW4; ++l)
      xs4[0][(st + l * 64) * 5 + sj] = pre[l];
  }

#pragma unroll 1
  for (int c = 0; c < 16; ++c) {        // 16 chunks of 16 dims
    __syncthreads();
    const int cur = c & 1;

    float4 nxt[SW4];
    if (c < 15) {
#pragma unroll
      for (int l = 0; l < SW4; ++l)
        nxt[l] = xb4[(size_t)(st + l * 64) * 64 + (c + 1) * 4 + sj];
    }

#pragma unroll
    for (int j = 0; j < 4; ++j) {
      const float4 xv = xs4[cur][tok * 5 + j];
      const float* Wc = W + c * 16 + j * 4;
#pragma unroll
      for (int q = 0; q < KPT; ++q) {
        const float4 wv = *reinterpret_cast<const float4*>(Wc + (kg * KPT + q) * DD);
        part[q] += dot4(xv, wv);
      }
    }

    if (c < 15) {
#pragma unroll
      for (int l = 0; l < SW4; ++l)
        xs4[cur ^ 1][(st + l * 64) * 5 + sj] = nxt[l];
    }
  }

  // masked softmax across NG thread-layers via psum exchange
  float e[KPT], pexp = 0.f;
#pragma unroll
  for (int q = 0; q < KPT; ++q) { e[q] = __expf(part[q]); pexp += e[q]; }
  psum[tok][kg] = pexp;
  __syncthreads();
  float a[KPT];
  {
    float denom = 0.f;
#pragma unroll
    for (int g = 0; g < NG; ++g) denom += psum[tok][g];
    const float r = mb[tok] ? (1.0f / denom) : 0.0f;
#pragma unroll
    for (int q = 0; q < KPT; ++q) a[q] = e[q] * r;
#pragma unroll
    for (int q4 = 0; q4 < KPT; q4 += 4)
      *reinterpret_cast<float4*>(&al[tok * KK + kg * KPT + q4]) =
          make_float4(a[q4], a[q4+1], a[q4+2], a[q4+3]);
  }

  // asum: butterfly over 64 lanes (= 64 distinct tokens per wave)
  {
    float red[KPT];
#pragma unroll
    for (int q = 0; q < KPT; ++q) red[q] = a[q];
#pragma unroll
    for (int off = 32; off >= 1; off >>= 1)
#pragma unroll
      for (int q = 0; q < KPT; ++q) red[q] += __shfl_xor(red[q], off);
    if (lane == 0)
#pragma unroll
      for (int q = 0; q < KPT; ++q) asacc[slot][kg * KPT + q] = red[q];
  }
  __syncthreads();

  // ------ Phase B: wave = k-quad (kq = wave*4), all TILE tokens -----------
  // Rolling 4-deep register pipeline: one load issued per token, consumed
  // 4 tokens later -> ~4 outstanding VMEM ops hide L1/L2/L3 latency.
  float4 acc0 = make_float4(0.f,0.f,0.f,0.f);
  float4 acc1 = make_float4(0.f,0.f,0.f,0.f);
  float4 acc2 = make_float4(0.f,0.f,0.f,0.f);
  float4 acc3 = make_float4(0.f,0.f,0.f,0.f);

  const float4* xw = xb4 + lane;        // lane owns dims 4*lane..4*lane+3
  const int kq4 = 4 * wave;             // this wave's k-quad offset in al row

  float4 w0 = xw[0], w1 = xw[64], w2 = xw[128], w3 = xw[192];

#pragma unroll 4
  for (int t = 0; t < TILE - 4; ++t) {
    const float4 nx = xw[(size_t)(t + 4) * 64];
    const float4 av = *reinterpret_cast<const float4*>(&al[t * KK + kq4]);
    acc0 = f4fma(av.x, w0, acc0);
    acc1 = f4fma(av.y, w0, acc1);
    acc2 = f4fma(av.z, w0, acc2);
    acc3 = f4fma(av.w, w0, acc3);
    w0 = w1; w1 = w2; w2 = w3; w3 = nx;
  }
#pragma unroll
  for (int t = TILE - 4; t < TILE; ++t) {
    const float4 av = *reinterpret_cast<const float4*>(&al[t * KK + kq4]);
    acc0 = f4fma(av.x, w0, acc0);
    acc1 = f4fma(av.y, w0, acc1);
    acc2 = f4fma(av.z, w0, acc2);
    acc3 = f4fma(av.w, w0, acc3);
    w0 = w1; w1 = w2; w2 = w3;
  }

  // ------------- output ----------------------------------------------------
  const int kq = wave * 4;
  if (partial_mode) {
    float4* dst = reinterpret_cast<float4*>(outv + (size_t)tile * KK * DD);
    dst[(kq + 0) * 64 + lane] = acc0;
    dst[(kq + 1) * 64 + lane] = acc1;
    dst[(kq + 2) * 64 + lane] = acc2;
    dst[(kq + 3) * 64 + lane] = acc3;
    if (tid < KK) {
      float s = 0.f;
#pragma unroll
      for (int sl = 0; sl < WPG; ++sl) s += asacc[sl][tid];
      outs[tile * KK + tid] = s;
    }
  } else {
    float* vb = outv + (size_t)b * KK * DD;
    const float4 aa4[4] = {acc0, acc1, acc2, acc3};
#pragma unroll
    for (int i = 0; i < 4; ++i) {
      float* p = vb + (kq + i) * DD + 4 * lane;
      atomicAdd(p + 0, aa4[i].x);
      atomicAdd(p + 1, aa4[i].y);
      atomicAdd(p + 2, aa4[i].z);
      atomicAdd(p + 3, aa4[i].w);
    }
    if (tid < KK) {
      float s = 0.f;
#pragma unroll
      for (int sl = 0; sl < WPG; ++sl) s += asacc[sl][tid];
      atomicAdd(&outs[b * KK + tid], s);
    }
  }
}

// ---------------------------------------------------------------------------
// Finalize A (BB*KK blocks x 256 thr): block = (b,k). float4 slice-sum with
// 4 slice-groups x 4 accumulators, LDS combine, ssum by wave butterfly.
// ---------------------------------------------------------------------------
__global__ __launch_bounds__(256) void finalizeA_kernel(
    const float* __restrict__ pv, const float* __restrict__ ps,
    const float* __restrict__ cent, float* __restrict__ vtmp,
    float* __restrict__ ssbuf, int nslice)
{
  const int blk = blockIdx.x;
  const int b   = blk >> 4;
  const int k   = blk & 15;
  const int tid = threadIdx.x;
  const int sg  = tid >> 6;           // slice group 0..3
  const int ld  = tid & 63;           // float4 dim index

  __shared__ float4 cmbA[3][64];

  float pval = 0.f;
  for (int s = ld; s < nslice; s += 64)
    pval += ps[(size_t)(b * nslice + s) * KK + k];
#pragma unroll
  for (int off = 32; off >= 1; off >>= 1) pval += __shfl_xor(pval, off);
  const float ssum = pval;

  const float4* pv4 = reinterpret_cast<const float4*>(pv);
  const size_t base = ((size_t)b * nslice * KK + k) * 64 + ld;
  float4 a0 = make_float4(0.f,0.f,0.f,0.f), a1 = a0, a2 = a0, a3 = a0;
  int s = sg;
  for (; s + 12 < nslice; s += 16) {
    a0 = f4add(a0, pv4[base + (size_t)(s     ) * (KK * 64)]);
    a1 = f4add(a1, pv4[base + (size_t)(s +  4) * (KK * 64)]);
    a2 = f4add(a2, pv4[base + (size_t)(s +  8) * (KK * 64)]);
    a3 = f4add(a3, pv4[base + (size_t)(s + 12) * (KK * 64)]);
  }
  for (; s < nslice; s += 4)
    a0 = f4add(a0, pv4[base + (size_t)s * (KK * 64)]);
  float4 tot = f4add(f4add(a0, a1), f4add(a2, a3));

  if (sg > 0) cmbA[sg - 1][ld] = tot;
  __syncthreads();

  if (sg == 0) {
    tot = f4add(tot, f4add(cmbA[0][ld], f4add(cmbA[1][ld], cmbA[2][ld])));
    const float4 cv = reinterpret_cast<const float4*>(cent)[k * 64 + ld];
    float4 v;
    v.x = tot.x - ssum * cv.x;
    v.y = tot.y - ssum * cv.y;
    v.z = tot.z - ssum * cv.z;
    v.w = tot.w - ssum * cv.w;
    reinterpret_cast<float4*>(vtmp)[((size_t)b * KK + k) * 64 + ld] = v;
    float p = dot4(v, v);
#pragma unroll
    for (int off = 32; off >= 1; off >>= 1) p += __shfl_xor(p, off);
    if (ld == 0) ssbuf[blk] = p;
  }
}

// ---------------------------------------------------------------------------
// Finalize B (BB blocks x 1024 thr): intra-cluster + global L2 normalize.
// ---------------------------------------------------------------------------
__global__ __launch_bounds__(1024) void finalizeB_kernel(
    const float* __restrict__ vtmp, const float* __restrict__ ssbuf,
    float* __restrict__ out)
{
  const int b    = blockIdx.x;
  const int tid  = threadIdx.x;
  const int d    = tid & 255;
  const int kq   = tid >> 8;
  const int lane = tid & 63;
  const int w    = tid >> 6;

  __shared__ float redB[16];
  __shared__ float gsh;

  float u[4];
  float p2 = 0.f;
#pragma unroll
  for (int kk = 0; kk < 4; ++kk) {
    const int k = kq * 4 + kk;
    const float rk = 1.0f / fmaxf(sqrtf(ssbuf[b * KK + k]), FEPS);
    u[kk] = vtmp[((size_t)b * KK + k) * DD + d] * rk;
    p2 += u[kk] * u[kk];
  }
#pragma unroll
  for (int off = 32; off >= 1; off >>= 1) p2 += __shfl_xor(p2, off);
  if (lane == 0) redB[w] = p2;
  __syncthreads();

  if (tid == 0) {
    float g = 0.f;
#pragma unroll
    for (int i = 0; i < 16; ++i) g += redB[i];
    gsh = 1.0f / fmaxf(sqrtf(g), FEPS);
  }
  __syncthreads();

  const float g = gsh;
#pragma unroll
  for (int kk = 0; kk < 4; ++kk) {
    const int k = kq * 4 + kk;
    out[(size_t)b * KK * DD + k * DD + d] = u[kk] * g;
  }
}

extern "C" void kernel_launch(void* const* d_in, const int* in_sizes, int n_in,
                              void* d_out, int out_size, void* d_ws, size_t ws_size,
                              hipStream_t stream) {
  const float* x    = (const float*)d_in[0];
  const int*   mask = (const int*)d_in[1];
  const float* W    = (const float*)d_in[2];
  const float* bias = (const float*)d_in[3];
  const float* cent = (const float*)d_in[4];
  float* out = (float*)d_out;

  const size_t vtmpN = (size_t)BB * KK * DD;
  const size_t ssN   = (size_t)BB * KK;

  const size_t t64   = (size_t)BB * (NN / 64);    // 2048 tiles
  const size_t t128  = (size_t)BB * (NN / 128);   // 1024 tiles
  const size_t need64  = (t64  * KK * DD + t64  * KK + vtmpN + ssN) * sizeof(float);
  const size_t need128 = (t128 * KK * DD + t128 * KK + vtmpN + ssN) * sizeof(float);

  if (ws_size >= need64) {
    float* pv    = (float*)d_ws;
    float* ps    = pv + t64 * KK * DD;
    float* vtmp  = ps + t64 * KK;
    float* ssbuf = vtmp + vtmpN;
    fused_kernel<64><<<(int)t64, 256, 0, stream>>>(x, mask, W, bias, pv, ps, 1);
    finalizeA_kernel<<<BB * KK, 256, 0, stream>>>(pv, ps, cent, vtmp, ssbuf, NN / 64);
    finalizeB_kernel<<<BB, 1024, 0, stream>>>(vtmp, ssbuf, out);
  } else if (ws_size >= need128) {
    float* pv    = (float*)d_ws;
    float* ps    = pv + t128 * KK * DD;
    float* vtmp  = ps + t128 * KK;
    float* ssbuf = vtmp + vtmpN;
    fused_kernel<128><<<(int)t128, 256, 0, stream>>>(x, mask, W, bias, pv, ps, 1);
    finalizeA_kernel<<<BB * KK, 256, 0, stream>>>(pv, ps, cent, vtmp, ssbuf, NN / 128);
    finalizeB_kernel<<<BB, 1024, 0, stream>>>(vtmp, ssbuf, out);
  } else {
    float* vacc  = (float*)d_ws;                 // [BB][KK][DD]
    float* sacc  = vacc + vtmpN;                 // [BB][KK]
    float* vtmp  = sacc + ssN;
    float* ssbuf = vtmp + vtmpN;
    hipMemsetAsync(d_ws, 0, (vtmpN + ssN) * sizeof(float), stream);
    fused_kernel<64><<<(int)t64, 256, 0, stream>>>(x, mask, W, bias, vacc, sacc, 0);
    finalizeA_kernel<<<BB * KK, 256, 0, stream>>>(vacc, sacc, cent, vtmp, ssbuf, 1);
    finalizeB_kernel<<<BB, 1024, 0, stream>>>(vtmp, ssbuf, out);
  }
}